// Round 9
// baseline (171.267 us; speedup 1.0000x reference)
//
#include <hip/hip_runtime.h>
#include <math.h>
#include <stdint.h>

typedef __bf16 bf16_t;
typedef __attribute__((ext_vector_type(8))) __bf16 bf16x8;
typedef __attribute__((ext_vector_type(4))) __bf16 bf16x4;
typedef __attribute__((ext_vector_type(4))) float f32x4;

#define DIM   768
#define HEADS 12
#define HD    64
#define NB    2
#define NQ    2048
#define NKV   2048
#define MROWS 4096
#define NQKV  2304   /* DIM(Q) + 2*DIM(KV) */

// ---- compile-safe fast exp2 (single v_exp_f32 when builtin exists) ----
__device__ __forceinline__ float fast_exp2(float x)
{
#if __has_builtin(__builtin_amdgcn_exp2f)
    return __builtin_amdgcn_exp2f(x);
#else
    return exp2f(x);
#endif
}

// ---- compile-safe pack: two fp32 -> bf16x2 (round-half-up), as uint32 ----
__device__ __forceinline__ uint32_t pack_bf16x2(float a, float b)
{
    const uint32_t lo = __builtin_bit_cast(uint32_t, a) + 0x8000u;
    const uint32_t hi = __builtin_bit_cast(uint32_t, b) + 0x8000u;
#if __has_builtin(__builtin_amdgcn_perm)
    return __builtin_amdgcn_perm(hi, lo, 0x07060302u);
#else
    return (lo >> 16) | (hi & 0xffff0000u);
#endif
}

// async 16B global -> LDS (m97 trick). LDS dest must be uniform + lane*16.
__device__ __forceinline__ void async_copy16(const bf16_t* g, bf16_t* l)
{
    typedef const __attribute__((address_space(1))) uint32_t* gp_t;
    typedef __attribute__((address_space(3))) uint32_t* lp_t;
    __builtin_amdgcn_global_load_lds((gp_t)(const void*)g, (lp_t)(void*)l, 16, 0, 0);
}

// ---------------- fused prep: casts (z=0,1) + weight transposes (z=2,3,4) ----------------
__global__ void prep_kernel(const float* __restrict__ qs, bf16_t* __restrict__ qs_bf,
                            const float* __restrict__ kvs, bf16_t* __restrict__ kvs_bf,
                            const float* __restrict__ Wq, const float* __restrict__ Wkv,
                            const float* __restrict__ Wproj, bf16_t* __restrict__ Wt,
                            float escale)
{
    __shared__ float tile[32][33];
    const int z = blockIdx.z;
    if (z < 2) {
        const float* in  = z ? kvs : qs;
        bf16_t*      out = z ? kvs_bf : qs_bf;
        const int i = (blockIdx.x * 256 + threadIdx.x) * 8;   // grid.x*2048 == MROWS*DIM
        bf16x8 v;
#pragma unroll
        for (int j = 0; j < 8; j++) v[j] = (bf16_t)in[i + j];
        *(bf16x8*)(out + i) = v;
        return;
    }
    const int N   = (z == 3) ? 2 * DIM : DIM;
    const int nb  = N / 32;
    const int idx = blockIdx.x;
    if (idx >= nb * (DIM / 32)) return;
    const float* W = (z == 2) ? Wq : (z == 3) ? Wkv : Wproj;
    bf16_t* T = Wt + ((z == 2) ? (size_t)0 : (z == 3) ? (size_t)DIM * DIM
                                                      : (size_t)NQKV * DIM);
    const float scl = (z == 2) ? escale : 1.0f;
    const int n0 = (idx % nb) * 32, k0 = (idx / nb) * 32;
    const int tx = threadIdx.x & 31, ty = threadIdx.x >> 5;
#pragma unroll
    for (int i = 0; i < 4; i++)
        tile[ty + i * 8][tx] = W[(size_t)(k0 + ty + i * 8) * N + n0 + tx];
    __syncthreads();
#pragma unroll
    for (int i = 0; i < 4; i++)
        T[(size_t)(n0 + ty + i * 8) * DIM + k0 + tx] = (bf16_t)(tile[tx][ty + i * 8] * scl);
}

// ---------------- GEMM: 128xTN tile, BK=64, async staging w/ global-side XOR swizzle --------
// MODE 0: fused QKV (N=2304). Q (pre-scaled via Wq) / K stored plain [b,tok,768];
//         V^T stored KV-PERMUTED so attn's PV A-frags are single contiguous b128.
// MODE 1: proj (fp32 out + bias)
template<int MODE, int TN>
__global__ __launch_bounds__(256)
void gemm_bk64(const bf16_t* __restrict__ Aq, const bf16_t* __restrict__ Akv,
               const bf16_t* __restrict__ Bt,
               bf16_t* __restrict__ Qb, bf16_t* __restrict__ Kb, bf16_t* __restrict__ Vtb,
               float* __restrict__ ofp, const float* __restrict__ bias)
{
    constexpr int K  = DIM;
    constexpr int NT = TN / 32;
    constexpr int ABLK = 128 * 64;
    constexpr int BBLK = TN * 64;
    constexpr int SELEMS = (MODE == 0) ? (128 * 136) : (ABLK + BBLK);
    __shared__ __align__(16) bf16_t smem[SELEMS];
    bf16_t* As = smem;
    bf16_t* Bs = smem + ABLK;

    const int tid  = threadIdx.x;
    const int wave = tid >> 6, lane = tid & 63;
    const int quad = lane >> 4, l16 = lane & 15, l7 = l16 & 7;
    const int bm = blockIdx.x * 128, bn = blockIdx.y * TN;
    const int wm = (wave >> 1) * 64, wn = (wave & 1) * (TN / 2);

    const bf16_t* A = (MODE == 0) ? (bn < DIM ? Aq : Akv) : Aq;

    const int srow = tid >> 3;
    const int scol = ((tid & 7) ^ (srow & 7)) * 8;
    const bf16_t* Ag[4];
    const bf16_t* Bg[NT];
#pragma unroll
    for (int i = 0; i < 4; i++)
        Ag[i] = A + (size_t)(bm + i * 32 + srow) * K + scol;
#pragma unroll
    for (int i = 0; i < NT; i++)
        Bg[i] = Bt + (size_t)(bn + i * 32 + srow) * K + scol;
    bf16_t* AsL = As + tid * 8;
    bf16_t* BsL = Bs + tid * 8;

    f32x4 acc[4][NT] = {};

    for (int k0 = 0; k0 < K; k0 += 64) {
#pragma unroll
        for (int i = 0; i < 4; i++) async_copy16(Ag[i] + k0, AsL + i * 2048);
#pragma unroll
        for (int i = 0; i < NT; i++) async_copy16(Bg[i] + k0, BsL + i * 2048);
        __syncthreads();
#pragma unroll
        for (int ks = 0; ks < 2; ks++) {
            const int pc = ((ks * 4 + quad) ^ l7) * 8;
            bf16x8 af[4], bfr[NT];
#pragma unroll
            for (int mt = 0; mt < 4; mt++)
                af[mt] = *(const bf16x8*)(&As[(wm + mt * 16 + l16) * 64 + pc]);
#pragma unroll
            for (int nt = 0; nt < NT; nt++)
                bfr[nt] = *(const bf16x8*)(&Bs[(wn + nt * 16 + l16) * 64 + pc]);
#pragma unroll
            for (int mt = 0; mt < 4; mt++)
#pragma unroll
                for (int nt = 0; nt < NT; nt++)
                    acc[mt][nt] = __builtin_amdgcn_mfma_f32_16x16x32_bf16(
                        af[mt], bfr[nt], acc[mt][nt], 0, 0, 0);
        }
        __syncthreads();
    }

    // ---- epilogue; C layout: col = lane&15, row = quad*4 + reg ----
    if (MODE == 1) {
#pragma unroll
        for (int mt = 0; mt < 4; mt++)
#pragma unroll
            for (int nt = 0; nt < NT; nt++)
#pragma unroll
                for (int r = 0; r < 4; r++) {
                    const int gm = bm + wm + mt * 16 + quad * 4 + r;
                    const int gn = bn + wn + nt * 16 + l16;
                    ofp[(size_t)gm * DIM + gn] = acc[mt][nt][r] + bias[gn];
                }
    } else if (bn < DIM) {
#pragma unroll
        for (int mt = 0; mt < 4; mt++)
#pragma unroll
            for (int nt = 0; nt < NT; nt++)
#pragma unroll
                for (int r = 0; r < 4; r++) {
                    const int gm = bm + wm + mt * 16 + quad * 4 + r;
                    const int gn = bn + wn + nt * 16 + l16;
                    Qb[(size_t)gm * DIM + gn] = (bf16_t)acc[mt][nt][r];
                }
    } else if (bn < 2 * DIM) {
#pragma unroll
        for (int mt = 0; mt < 4; mt++)
#pragma unroll
            for (int nt = 0; nt < NT; nt++)
#pragma unroll
                for (int r = 0; r < 4; r++) {
                    const int gm = bm + wm + mt * 16 + quad * 4 + r;
                    const int gn = bn + wn + nt * 16 + l16 - DIM;
                    Kb[(size_t)gm * DIM + gn] = (bf16_t)acc[mt][nt][r];
                }
    } else {
        // V^T: transpose through LDS, then KV-PERMUTED coalesced 16B stores
        bf16_t* tr = smem;
#pragma unroll
        for (int mt = 0; mt < 4; mt++)
#pragma unroll
            for (int nt = 0; nt < NT; nt++) {
                bf16x4 tv;
#pragma unroll
                for (int r = 0; r < 4; r++) tv[r] = (bf16_t)acc[mt][nt][r];
                *(bf16x4*)(&tr[(wn + nt * 16 + l16) * 136 + wm + mt * 16 + quad * 4]) = tv;
            }
        __syncthreads();
        const int b = bm >> 11, kv0 = bm & 2047;
        const int n2base = bn - 2 * DIM;
        const int cg = tid & 15, cc = cg >> 2, cq = cg & 3;
#pragma unroll
        for (int i = 0; i < 8; i++) {
            const int row = i * 16 + (tid >> 4);
            const int n2 = n2base + row, h = n2 >> 6, d = n2 & 63;
            const bf16x4 lo4 = *(const bf16x4*)(&tr[row * 136 + cc * 32 + cq * 4]);
            const bf16x4 hi4 = *(const bf16x4*)(&tr[row * 136 + cc * 32 + 16 + cq * 4]);
            bf16x8 vv;
#pragma unroll
            for (int j = 0; j < 4; j++) { vv[j] = lo4[j]; vv[4 + j] = hi4[j]; }
            *(bf16x8*)(Vtb + ((size_t)(b * HEADS + h) * HD + d) * NKV + kv0 + cg * 8) = vv;
        }
    }
}

// ---------------- flash attention: double-buffered staging, 1 barrier/iter ----------------
// grid (NB*HEADS, NQ/64). 4 waves: wave=(qh,kvh); wave computes 32 q x its 64-kv half.
// K[128x64] + V^T[64x128] (producer k-permuted) staged via global_load_lds(16B) into a
// 2x32KB double buffer; bank-XOR swizzle folded into the GLOBAL gather addresses for
// BOTH K and V (must match the ^l7 applied at the LDS fragment reads!).
// stage(t+1) issued right after barrier(t) -> next barrier's vmcnt drain overlaps a
// full iteration of compute. No-max softmax -> pairwise kv-half merge at end.
__global__ __launch_bounds__(256, 2)
void attn_kernel(const bf16_t* __restrict__ Qb, const bf16_t* __restrict__ Kb,
                 const bf16_t* __restrict__ Vt, bf16_t* __restrict__ Xb)
{
    __shared__ __align__(16) bf16_t kvbuf[2][16384];   // per buf: K [0,8192) V [8192,16384)
    __shared__ float libuf[4][2][16];

    const int tid  = threadIdx.x;
    const int wave = tid >> 6, lane = tid & 63;
    const int quad = lane >> 4, l16 = lane & 15;
    const int l7   = l16 & 7;
    const int qh = wave & 1, kvh = wave >> 1;
    const int bh = blockIdx.x;
    const int b = bh / HEADS, h = bh % HEADS;
    const int q0 = blockIdx.y * 64;

    const bf16_t* Qp = Qb + (size_t)b * NQ * DIM + h * HD;
    const bf16_t* Kp = Kb + (size_t)b * NKV * DIM + h * HD;
    const bf16_t* Vp = Vt + (size_t)(b * HEADS + h) * HD * NKV;

    // Q B-frags (reg-resident): q = q0+qh*32+qt*16+l16, k = ks*32+quad*8+j
    bf16x8 qf[2][2];
#pragma unroll
    for (int qt = 0; qt < 2; qt++)
#pragma unroll
        for (int ks = 0; ks < 2; ks++)
            qf[qt][ks] = *(const bf16x8*)(Qp + (size_t)(q0 + qh * 32 + qt * 16 + l16) * DIM
                                          + ks * 32 + quad * 8);

    // K staging: row r=wave*32+i*8+(lane>>3); phys chunk lane&7 holds logical (lane&7)^(r&7)
    const int kl8 = lane >> 3;
    const bf16_t* Kg0 = Kp + (size_t)(wave * 32 + kl8) * DIM + (((lane & 7) ^ kl8) * 8);
    // V staging: d=wave*16+i*4+(lane>>4); phys p=lane&15 holds chunk (p&8)|((p&7)^(d&7))
    // (bank-XOR in global gather — MUST mirror the ^l7 at the fragment read)
    const int vl4 = lane >> 4, vp = lane & 15;
    const bf16_t* Vg0[4];
#pragma unroll
    for (int i = 0; i < 4; i++) {
        const int d = wave * 16 + i * 4 + vl4;
        const int c = (vp & 8) | ((vp & 7) ^ (d & 7));
        Vg0[i] = Vp + (size_t)d * NKV + c * 8;
    }

    f32x4 o[4][2] = {};
    float li[2] = {0.0f, 0.0f};

    // prologue: stage tile 0 into buf 0
#pragma unroll
    for (int i = 0; i < 4; i++)
        async_copy16(Kg0 + (size_t)(i * 8) * DIM, &kvbuf[0][wave * 2048 + lane * 8 + i * 512]);
#pragma unroll
    for (int i = 0; i < 4; i++)
        async_copy16(Vg0[i], &kvbuf[0][8192 + wave * 2048 + lane * 8 + i * 512]);

    for (int t = 0; t < NKV / 128; t++) {
        __syncthreads();   // vmcnt drain: tile t staged (overlapped with iter t-1 compute)
        if (t + 1 < NKV / 128) {
            const int kv1 = (t + 1) * 128;
            bf16_t* dst = kvbuf[(t + 1) & 1];
#pragma unroll
            for (int i = 0; i < 4; i++)
                async_copy16(Kg0 + (size_t)(kv1 + i * 8) * DIM,
                             dst + wave * 2048 + lane * 8 + i * 512);
#pragma unroll
            for (int i = 0; i < 4; i++)
                async_copy16(Vg0[i] + kv1, dst + 8192 + wave * 2048 + lane * 8 + i * 512);
        }
        const bf16_t* kb = kvbuf[t & 1];

        // S^T = K @ Q^T : lane holds S^T[kv = kvh*64 + kt*16 + quad*4 + r][q = l16]
        f32x4 s[4][2] = {};
#pragma unroll
        for (int kt = 0; kt < 4; kt++)
#pragma unroll
            for (int ks = 0; ks < 2; ks++) {
                const bf16x8 kf = *(const bf16x8*)(&kb[
                    (kvh * 64 + kt * 16 + l16) * 64 + ((((ks << 2) | quad) ^ l7) * 8)]);
#pragma unroll
                for (int qt = 0; qt < 2; qt++)
                    s[kt][qt] = __builtin_amdgcn_mfma_f32_16x16x32_bf16(
                        kf, qf[qt][ks], s[kt][qt], 0, 0, 0);
            }

        // softmax (no max-subtraction) + pack to permuted-k PV B-frags
        bf16x8 pb[2][2];
#pragma unroll
        for (int qt = 0; qt < 2; qt++) {
            float p[16];
#pragma unroll
            for (int kt = 0; kt < 4; kt++)
#pragma unroll
                for (int r = 0; r < 4; r++) p[kt * 4 + r] = fast_exp2(s[kt][qt][r]);
            float rs = 0.0f;
#pragma unroll
            for (int j = 0; j < 16; j++) rs += p[j];
            li[qt] += rs;
#pragma unroll
            for (int kc = 0; kc < 2; kc++) {
                union { uint32_t u[4]; bf16x8 v; } pu;
#pragma unroll
                for (int i = 0; i < 4; i++)
                    pu.u[i] = pack_bf16x2(p[kc * 8 + 2 * i], p[kc * 8 + 2 * i + 1]);
                pb[qt][kc] = pu.v;
            }
        }

        // O^T += V^T @ P^T : producer-permuted V -> single b128 per A-frag
#pragma unroll
        for (int dt = 0; dt < 4; dt++) {
            const int droff = 8192 + (dt * 16 + l16) * 128;
#pragma unroll
            for (int kc = 0; kc < 2; kc++) {
                const bf16x8 vf = *(const bf16x8*)(&kb[
                    droff + (kvh * 8 + ((kc * 4 + quad) ^ l7)) * 8]);
#pragma unroll
                for (int qt = 0; qt < 2; qt++)
                    o[dt][qt] = __builtin_amdgcn_mfma_f32_16x16x32_bf16(
                        vf, pb[qt][kc], o[dt][qt], 0, 0, 0);
            }
        }
    }

    // li: reduce across quads (quads covered disjoint kv rows)
#pragma unroll
    for (int qt = 0; qt < 2; qt++) {
        li[qt] += __shfl_xor(li[qt], 16);
        li[qt] += __shfl_xor(li[qt], 32);
    }
    if (quad == 0) { libuf[wave][0][l16] = li[0]; libuf[wave][1][l16] = li[1]; }

    // pairwise kv-half merge in buf0 (last compute read buf1)
    float* ob = (float*)(&kvbuf[0][0] + qh * 8192);
    if (kvh == 1) {
#pragma unroll
        for (int dt = 0; dt < 4; dt++)
#pragma unroll
            for (int qt = 0; qt < 2; qt++)
#pragma unroll
                for (int r = 0; r < 4; r++)
                    ob[(dt * 16 + quad * 4 + r) * 33 + qt * 16 + l16] = o[dt][qt][r];
    }
    __syncthreads();
    if (kvh == 0) {
        const float inv0 = 1.0f / (li[0] + libuf[2 + qh][0][l16]);
        const float inv1 = 1.0f / (li[1] + libuf[2 + qh][1][l16]);
#pragma unroll
        for (int dt = 0; dt < 4; dt++)
#pragma unroll
            for (int qt = 0; qt < 2; qt++)
#pragma unroll
                for (int r = 0; r < 4; r++)
                    o[dt][qt][r] = (o[dt][qt][r]
                                    + ob[(dt * 16 + quad * 4 + r) * 33 + qt * 16 + l16])
                                   * (qt ? inv1 : inv0);
    }
    __syncthreads();
    bf16_t* Ob16 = &kvbuf[0][0];   // [64 q][72 d] = 9216 B
    if (kvh == 0) {
#pragma unroll
        for (int dt = 0; dt < 4; dt++)
#pragma unroll
            for (int qt = 0; qt < 2; qt++) {
                bf16x4 ov;
#pragma unroll
                for (int r = 0; r < 4; r++) ov[r] = (bf16_t)o[dt][qt][r];
                *(bf16x4*)(&Ob16[(qh * 32 + qt * 16 + l16) * 72 + dt * 16 + quad * 4]) = ov;
            }
    }
    __syncthreads();
    {
        const int row = tid >> 2, ch = (tid & 3) * 16;
        bf16_t* dst = Xb + (size_t)(b * NQ + q0 + row) * DIM + h * HD + ch;
        *(bf16x8*)(dst)     = *(const bf16x8*)(&Ob16[row * 72 + ch]);
        *(bf16x8*)(dst + 8) = *(const bf16x8*)(&Ob16[row * 72 + ch + 8]);
    }
}

extern "C" void kernel_launch(void* const* d_in, const int* in_sizes, int n_in,
                              void* d_out, int out_size, void* d_ws, size_t ws_size,
                              hipStream_t stream)
{
    const float* qs    = (const float*)d_in[0];
    const float* kvs   = (const float*)d_in[1];
    const float* Wq    = (const float*)d_in[2];
    const float* Wkv   = (const float*)d_in[3];
    const float* Wproj = (const float*)d_in[4];
    const float* bproj = (const float*)d_in[5];
    float* out = (float*)d_out;

    bf16_t* w = (bf16_t*)d_ws;
    bf16_t* qs_bf  = w;  w += (size_t)MROWS * DIM;
    bf16_t* kvs_bf = w;  w += (size_t)MROWS * DIM;
    bf16_t* Wt     = w;  w += (size_t)NQKV * DIM;   // Wqt | Wkvt contiguous
    bf16_t* Wprojt = w;  w += (size_t)DIM * DIM;
    bf16_t* Qb     = w;  w += (size_t)MROWS * DIM;
    bf16_t* Kb     = w;  w += (size_t)MROWS * DIM;
    bf16_t* Vtb    = w;  w += (size_t)MROWS * DIM;
    bf16_t* Xb     = qs_bf;   // qs_bf dead after QKV GEMM

    const float escale = 0.125f * 1.44269504088896341f;  // Dh^-0.5 * log2(e), folded into Wq
    prep_kernel<<<dim3(MROWS * DIM / 2048, 1, 5), 256, 0, stream>>>(
        qs, qs_bf, kvs, kvs_bf, Wq, Wkv, Wproj, Wt, escale);

    gemm_bk64<0, 128><<<dim3(MROWS / 128, NQKV / 128), 256, 0, stream>>>(
        qs_bf, kvs_bf, Wt, Qb, Kb, Vtb, nullptr, nullptr);
    attn_kernel<<<dim3(NB * HEADS, NQ / 64), 256, 0, stream>>>(Qb, Kb, Vtb, Xb);
    gemm_bk64<1, 64><<<dim3(MROWS / 128, DIM / 64), 256, 0, stream>>>(
        Xb, nullptr, Wprojt, nullptr, nullptr, nullptr, out, bproj);
}

// Round 10
// 160.621 us; speedup vs baseline: 1.0663x; 1.0663x over previous
//
#include <hip/hip_runtime.h>
#include <math.h>
#include <stdint.h>

typedef __bf16 bf16_t;
typedef __attribute__((ext_vector_type(8))) __bf16 bf16x8;
typedef __attribute__((ext_vector_type(4))) __bf16 bf16x4;
typedef __attribute__((ext_vector_type(4))) float f32x4;

#define DIM   768
#define HEADS 12
#define HD    64
#define NB    2
#define NQ    2048
#define NKV   2048
#define MROWS 4096
#define NQKV  2304   /* DIM(Q) + 2*DIM(KV) */

// ---- compile-safe fast exp2 (single v_exp_f32 when builtin exists) ----
__device__ __forceinline__ float fast_exp2(float x)
{
#if __has_builtin(__builtin_amdgcn_exp2f)
    return __builtin_amdgcn_exp2f(x);
#else
    return exp2f(x);
#endif
}

// ---- compile-safe pack: two fp32 -> bf16x2 (round-half-up), as uint32 ----
__device__ __forceinline__ uint32_t pack_bf16x2(float a, float b)
{
    const uint32_t lo = __builtin_bit_cast(uint32_t, a) + 0x8000u;
    const uint32_t hi = __builtin_bit_cast(uint32_t, b) + 0x8000u;
#if __has_builtin(__builtin_amdgcn_perm)
    return __builtin_amdgcn_perm(hi, lo, 0x07060302u);
#else
    return (lo >> 16) | (hi & 0xffff0000u);
#endif
}

// async 16B global -> LDS (m97 trick). LDS dest must be uniform + lane*16.
__device__ __forceinline__ void async_copy16(const bf16_t* g, bf16_t* l)
{
    typedef const __attribute__((address_space(1))) uint32_t* gp_t;
    typedef __attribute__((address_space(3))) uint32_t* lp_t;
    __builtin_amdgcn_global_load_lds((gp_t)(const void*)g, (lp_t)(void*)l, 16, 0, 0);
}

// ---------------- fused prep: casts (z=0,1) + weight transposes (z=2,3,4) ----------------
__global__ void prep_kernel(const float* __restrict__ qs, bf16_t* __restrict__ qs_bf,
                            const float* __restrict__ kvs, bf16_t* __restrict__ kvs_bf,
                            const float* __restrict__ Wq, const float* __restrict__ Wkv,
                            const float* __restrict__ Wproj, bf16_t* __restrict__ Wt,
                            float escale)
{
    __shared__ float tile[32][33];
    const int z = blockIdx.z;
    if (z < 2) {
        const float* in  = z ? kvs : qs;
        bf16_t*      out = z ? kvs_bf : qs_bf;
        const int i = (blockIdx.x * 256 + threadIdx.x) * 8;   // grid.x*2048 == MROWS*DIM
        bf16x8 v;
#pragma unroll
        for (int j = 0; j < 8; j++) v[j] = (bf16_t)in[i + j];
        *(bf16x8*)(out + i) = v;
        return;
    }
    const int N   = (z == 3) ? 2 * DIM : DIM;
    const int nb  = N / 32;
    const int idx = blockIdx.x;
    if (idx >= nb * (DIM / 32)) return;
    const float* W = (z == 2) ? Wq : (z == 3) ? Wkv : Wproj;
    bf16_t* T = Wt + ((z == 2) ? (size_t)0 : (z == 3) ? (size_t)DIM * DIM
                                                      : (size_t)NQKV * DIM);
    const float scl = (z == 2) ? escale : 1.0f;
    const int n0 = (idx % nb) * 32, k0 = (idx / nb) * 32;
    const int tx = threadIdx.x & 31, ty = threadIdx.x >> 5;
#pragma unroll
    for (int i = 0; i < 4; i++)
        tile[ty + i * 8][tx] = W[(size_t)(k0 + ty + i * 8) * N + n0 + tx];
    __syncthreads();
#pragma unroll
    for (int i = 0; i < 4; i++)
        T[(size_t)(n0 + ty + i * 8) * DIM + k0 + tx] = (bf16_t)(tile[tx][ty + i * 8] * scl);
}

// ---------------- GEMM: 128xTN tile, BK=64, async staging w/ global-side XOR swizzle --------
// MODE 0: fused QKV (N=2304). Q (pre-scaled via Wq) / K stored plain [b,tok,768];
//         V^T stored KV-PERMUTED so attn's PV A-frags are single contiguous b128.
// MODE 1: proj (fp32 out + bias)
template<int MODE, int TN>
__global__ __launch_bounds__(256)
void gemm_bk64(const bf16_t* __restrict__ Aq, const bf16_t* __restrict__ Akv,
               const bf16_t* __restrict__ Bt,
               bf16_t* __restrict__ Qb, bf16_t* __restrict__ Kb, bf16_t* __restrict__ Vtb,
               float* __restrict__ ofp, const float* __restrict__ bias)
{
    constexpr int K  = DIM;
    constexpr int NT = TN / 32;
    constexpr int ABLK = 128 * 64;
    constexpr int BBLK = TN * 64;
    constexpr int SELEMS = (MODE == 0) ? (128 * 136) : (ABLK + BBLK);
    __shared__ __align__(16) bf16_t smem[SELEMS];
    bf16_t* As = smem;
    bf16_t* Bs = smem + ABLK;

    const int tid  = threadIdx.x;
    const int wave = tid >> 6, lane = tid & 63;
    const int quad = lane >> 4, l16 = lane & 15, l7 = l16 & 7;
    const int bm = blockIdx.x * 128, bn = blockIdx.y * TN;
    const int wm = (wave >> 1) * 64, wn = (wave & 1) * (TN / 2);

    const bf16_t* A = (MODE == 0) ? (bn < DIM ? Aq : Akv) : Aq;

    const int srow = tid >> 3;
    const int scol = ((tid & 7) ^ (srow & 7)) * 8;
    const bf16_t* Ag[4];
    const bf16_t* Bg[NT];
#pragma unroll
    for (int i = 0; i < 4; i++)
        Ag[i] = A + (size_t)(bm + i * 32 + srow) * K + scol;
#pragma unroll
    for (int i = 0; i < NT; i++)
        Bg[i] = Bt + (size_t)(bn + i * 32 + srow) * K + scol;
    bf16_t* AsL = As + tid * 8;
    bf16_t* BsL = Bs + tid * 8;

    f32x4 acc[4][NT] = {};

    for (int k0 = 0; k0 < K; k0 += 64) {
#pragma unroll
        for (int i = 0; i < 4; i++) async_copy16(Ag[i] + k0, AsL + i * 2048);
#pragma unroll
        for (int i = 0; i < NT; i++) async_copy16(Bg[i] + k0, BsL + i * 2048);
        __syncthreads();
#pragma unroll
        for (int ks = 0; ks < 2; ks++) {
            const int pc = ((ks * 4 + quad) ^ l7) * 8;
            bf16x8 af[4], bfr[NT];
#pragma unroll
            for (int mt = 0; mt < 4; mt++)
                af[mt] = *(const bf16x8*)(&As[(wm + mt * 16 + l16) * 64 + pc]);
#pragma unroll
            for (int nt = 0; nt < NT; nt++)
                bfr[nt] = *(const bf16x8*)(&Bs[(wn + nt * 16 + l16) * 64 + pc]);
#pragma unroll
            for (int mt = 0; mt < 4; mt++)
#pragma unroll
                for (int nt = 0; nt < NT; nt++)
                    acc[mt][nt] = __builtin_amdgcn_mfma_f32_16x16x32_bf16(
                        af[mt], bfr[nt], acc[mt][nt], 0, 0, 0);
        }
        __syncthreads();
    }

    // ---- epilogue; C layout: col = lane&15, row = quad*4 + reg ----
    if (MODE == 1) {
#pragma unroll
        for (int mt = 0; mt < 4; mt++)
#pragma unroll
            for (int nt = 0; nt < NT; nt++)
#pragma unroll
                for (int r = 0; r < 4; r++) {
                    const int gm = bm + wm + mt * 16 + quad * 4 + r;
                    const int gn = bn + wn + nt * 16 + l16;
                    ofp[(size_t)gm * DIM + gn] = acc[mt][nt][r] + bias[gn];
                }
    } else if (bn < DIM) {
#pragma unroll
        for (int mt = 0; mt < 4; mt++)
#pragma unroll
            for (int nt = 0; nt < NT; nt++)
#pragma unroll
                for (int r = 0; r < 4; r++) {
                    const int gm = bm + wm + mt * 16 + quad * 4 + r;
                    const int gn = bn + wn + nt * 16 + l16;
                    Qb[(size_t)gm * DIM + gn] = (bf16_t)acc[mt][nt][r];
                }
    } else if (bn < 2 * DIM) {
#pragma unroll
        for (int mt = 0; mt < 4; mt++)
#pragma unroll
            for (int nt = 0; nt < NT; nt++)
#pragma unroll
                for (int r = 0; r < 4; r++) {
                    const int gm = bm + wm + mt * 16 + quad * 4 + r;
                    const int gn = bn + wn + nt * 16 + l16 - DIM;
                    Kb[(size_t)gm * DIM + gn] = (bf16_t)acc[mt][nt][r];
                }
    } else {
        // V^T: transpose through LDS, then KV-PERMUTED coalesced 16B stores
        bf16_t* tr = smem;
#pragma unroll
        for (int mt = 0; mt < 4; mt++)
#pragma unroll
            for (int nt = 0; nt < NT; nt++) {
                bf16x4 tv;
#pragma unroll
                for (int r = 0; r < 4; r++) tv[r] = (bf16_t)acc[mt][nt][r];
                *(bf16x4*)(&tr[(wn + nt * 16 + l16) * 136 + wm + mt * 16 + quad * 4]) = tv;
            }
        __syncthreads();
        const int b = bm >> 11, kv0 = bm & 2047;
        const int n2base = bn - 2 * DIM;
        const int cg = tid & 15, cc = cg >> 2, cq = cg & 3;
#pragma unroll
        for (int i = 0; i < 8; i++) {
            const int row = i * 16 + (tid >> 4);
            const int n2 = n2base + row, h = n2 >> 6, d = n2 & 63;
            const bf16x4 lo4 = *(const bf16x4*)(&tr[row * 136 + cc * 32 + cq * 4]);
            const bf16x4 hi4 = *(const bf16x4*)(&tr[row * 136 + cc * 32 + 16 + cq * 4]);
            bf16x8 vv;
#pragma unroll
            for (int j = 0; j < 4; j++) { vv[j] = lo4[j]; vv[4 + j] = hi4[j]; }
            *(bf16x8*)(Vtb + ((size_t)(b * HEADS + h) * HD + d) * NKV + kv0 + cg * 8) = vv;
        }
    }
}

// ---------------- flash attention: single-buffer LDS staging (round-7-verified) ----------------
// grid (NB*HEADS, NQ/64). 4 waves: wave=(qh,kvh); wave computes 32 q x its 64-kv half.
// K[128x64] and V^T[64x128] staged via global_load_lds(16B), bank-XOR folded into the
// GLOBAL gather address. V^T is producer-permuted so PV A-frags are single b128.
// launch_bounds(256,4): 33KB LDS + <=128 VGPR -> 4 blocks/CU for barrier latency hiding.
__global__ __launch_bounds__(256, 4)
void attn_kernel(const bf16_t* __restrict__ Qb, const bf16_t* __restrict__ Kb,
                 const bf16_t* __restrict__ Vt, bf16_t* __restrict__ Xb)
{
    __shared__ __align__(16) bf16_t kvbuf[16384];   // K:[0,8192) V:[8192,16384) elems
    __shared__ float libuf[4][2][16];

    const int tid  = threadIdx.x;
    const int wave = tid >> 6, lane = tid & 63;
    const int quad = lane >> 4, l16 = lane & 15;
    const int l7   = l16 & 7;
    const int qh = wave & 1, kvh = wave >> 1;
    const int bh = blockIdx.x;
    const int b = bh / HEADS, h = bh % HEADS;
    const int q0 = blockIdx.y * 64;

    const bf16_t* Qp = Qb + (size_t)b * NQ * DIM + h * HD;
    const bf16_t* Kp = Kb + (size_t)b * NKV * DIM + h * HD;
    const bf16_t* Vp = Vt + (size_t)(b * HEADS + h) * HD * NKV;

    // Q B-frags (reg-resident, pre-scaled): q = q0+qh*32+qt*16+l16, k = ks*32+quad*8+j
    bf16x8 qf[2][2];
#pragma unroll
    for (int qt = 0; qt < 2; qt++)
#pragma unroll
        for (int ks = 0; ks < 2; ks++)
            qf[qt][ks] = *(const bf16x8*)(Qp + (size_t)(q0 + qh * 32 + qt * 16 + l16) * DIM
                                          + ks * 32 + quad * 8);

    // K staging: row r=wave*32+i*8+(lane>>3); phys chunk lane&7 holds logical (lane&7)^(r&7)
    const int kl8 = lane >> 3;
    const bf16_t* Kg0 = Kp + (size_t)(wave * 32 + kl8) * DIM + (((lane & 7) ^ kl8) * 8);
    // V staging: d=wave*16+i*4+(lane>>4); phys p=lane&15 holds chunk (p&8)|((p&7)^(d&7))
    const int vl4 = lane >> 4, vp = lane & 15;
    const bf16_t* Vg0[4];
#pragma unroll
    for (int i = 0; i < 4; i++) {
        const int d = wave * 16 + i * 4 + vl4;
        const int c = (vp & 8) | ((vp & 7) ^ (d & 7));
        Vg0[i] = Vp + (size_t)d * NKV + c * 8;
    }
    bf16_t* KgL = kvbuf + wave * 2048 + lane * 8;
    bf16_t* VgL = kvbuf + 8192 + wave * 2048 + lane * 8;

    f32x4 o[4][2] = {};
    float li[2] = {0.0f, 0.0f};

    for (int t = 0; t < NKV / 128; t++) {
        const int kv0 = t * 128;
#pragma unroll
        for (int i = 0; i < 4; i++)
            async_copy16(Kg0 + (size_t)(kv0 + i * 8) * DIM, KgL + i * 512);
#pragma unroll
        for (int i = 0; i < 4; i++)
            async_copy16(Vg0[i] + kv0, VgL + i * 512);
        __syncthreads();

        // S^T = K @ Q^T : lane holds S^T[kv = kvh*64 + kt*16 + quad*4 + r][q = l16]
        f32x4 s[4][2] = {};
#pragma unroll
        for (int kt = 0; kt < 4; kt++)
#pragma unroll
            for (int ks = 0; ks < 2; ks++) {
                const bf16x8 kf = *(const bf16x8*)(&kvbuf[
                    (kvh * 64 + kt * 16 + l16) * 64 + ((((ks << 2) | quad) ^ l7) * 8)]);
#pragma unroll
                for (int qt = 0; qt < 2; qt++)
                    s[kt][qt] = __builtin_amdgcn_mfma_f32_16x16x32_bf16(
                        kf, qf[qt][ks], s[kt][qt], 0, 0, 0);
            }

        // softmax (no max-subtraction) + pack to permuted-k PV B-frags
        bf16x8 pb[2][2];
#pragma unroll
        for (int qt = 0; qt < 2; qt++) {
            float p[16];
#pragma unroll
            for (int kt = 0; kt < 4; kt++)
#pragma unroll
                for (int r = 0; r < 4; r++) p[kt * 4 + r] = fast_exp2(s[kt][qt][r]);
            float rs = 0.0f;
#pragma unroll
            for (int j = 0; j < 16; j++) rs += p[j];
            li[qt] += rs;
#pragma unroll
            for (int kc = 0; kc < 2; kc++) {
                union { uint32_t u[4]; bf16x8 v; } pu;
#pragma unroll
                for (int i = 0; i < 4; i++)
                    pu.u[i] = pack_bf16x2(p[kc * 8 + 2 * i], p[kc * 8 + 2 * i + 1]);
                pb[qt][kc] = pu.v;
            }
        }

        // O^T += V^T @ P^T : producer-permuted V -> single b128 per A-frag
#pragma unroll
        for (int dt = 0; dt < 4; dt++) {
            const int droff = 8192 + (dt * 16 + l16) * 128;
#pragma unroll
            for (int kc = 0; kc < 2; kc++) {
                const bf16x8 vf = *(const bf16x8*)(&kvbuf[
                    droff + (kvh * 8 + ((kc * 4 + quad) ^ l7)) * 8]);
#pragma unroll
                for (int qt = 0; qt < 2; qt++)
                    o[dt][qt] = __builtin_amdgcn_mfma_f32_16x16x32_bf16(
                        vf, pb[qt][kc], o[dt][qt], 0, 0, 0);
            }
        }
        __syncthreads();
    }

    // li: reduce across quads (quads covered disjoint kv rows)
#pragma unroll
    for (int qt = 0; qt < 2; qt++) {
        li[qt] += __shfl_xor(li[qt], 16);
        li[qt] += __shfl_xor(li[qt], 32);
    }
    if (quad == 0) { libuf[wave][0][l16] = li[0]; libuf[wave][1][l16] = li[1]; }

    // pairwise kv-half merge (aliases kvbuf halves; 64x33 f32 each)
    float* ob = (float*)(kvbuf + qh * 8192);
    if (kvh == 1) {
#pragma unroll
        for (int dt = 0; dt < 4; dt++)
#pragma unroll
            for (int qt = 0; qt < 2; qt++)
#pragma unroll
                for (int r = 0; r < 4; r++)
                    ob[(dt * 16 + quad * 4 + r) * 33 + qt * 16 + l16] = o[dt][qt][r];
    }
    __syncthreads();
    if (kvh == 0) {
        const float inv0 = 1.0f / (li[0] + libuf[2 + qh][0][l16]);
        const float inv1 = 1.0f / (li[1] + libuf[2 + qh][1][l16]);
#pragma unroll
        for (int dt = 0; dt < 4; dt++)
#pragma unroll
            for (int qt = 0; qt < 2; qt++)
#pragma unroll
                for (int r = 0; r < 4; r++)
                    o[dt][qt][r] = (o[dt][qt][r]
                                    + ob[(dt * 16 + quad * 4 + r) * 33 + qt * 16 + l16])
                                   * (qt ? inv1 : inv0);
    }
    __syncthreads();
    bf16_t* Ob16 = kvbuf;   // [64 q][72 d] = 9216 B
    if (kvh == 0) {
#pragma unroll
        for (int dt = 0; dt < 4; dt++)
#pragma unroll
            for (int qt = 0; qt < 2; qt++) {
                bf16x4 ov;
#pragma unroll
                for (int r = 0; r < 4; r++) ov[r] = (bf16_t)o[dt][qt][r];
                *(bf16x4*)(&Ob16[(qh * 32 + qt * 16 + l16) * 72 + dt * 16 + quad * 4]) = ov;
            }
    }
    __syncthreads();
    {
        const int row = tid >> 2, ch = (tid & 3) * 16;
        bf16_t* dst = Xb + (size_t)(b * NQ + q0 + row) * DIM + h * HD + ch;
        *(bf16x8*)(dst)     = *(const bf16x8*)(&Ob16[row * 72 + ch]);
        *(bf16x8*)(dst + 8) = *(const bf16x8*)(&Ob16[row * 72 + ch + 8]);
    }
}

extern "C" void kernel_launch(void* const* d_in, const int* in_sizes, int n_in,
                              void* d_out, int out_size, void* d_ws, size_t ws_size,
                              hipStream_t stream)
{
    const float* qs    = (const float*)d_in[0];
    const float* kvs   = (const float*)d_in[1];
    const float* Wq    = (const float*)d_in[2];
    const float* Wkv   = (const float*)d_in[3];
    const float* Wproj = (const float*)d_in[4];
    const float* bproj = (const float*)d_in[5];
    float* out = (float*)d_out;

    bf16_t* w = (bf16_t*)d_ws;
    bf16_t* qs_bf  = w;  w += (size_t)MROWS * DIM;
    bf16_t* kvs_bf = w;  w += (size_t)MROWS * DIM;
    bf16_t* Wt     = w;  w += (size_t)NQKV * DIM;   // Wqt | Wkvt contiguous
    bf16_t* Wprojt = w;  w += (size_t)DIM * DIM;
    bf16_t* Qb     = w;  w += (size_t)MROWS * DIM;
    bf16_t* Kb     = w;  w += (size_t)MROWS * DIM;
    bf16_t* Vtb    = w;  w += (size_t)MROWS * DIM;
    bf16_t* Xb     = qs_bf;   // qs_bf dead after QKV GEMM

    const float escale = 0.125f * 1.44269504088896341f;  // Dh^-0.5 * log2(e), folded into Wq
    prep_kernel<<<dim3(MROWS * DIM / 2048, 1, 5), 256, 0, stream>>>(
        qs, qs_bf, kvs, kvs_bf, Wq, Wkv, Wproj, Wt, escale);

    gemm_bk64<0, 128><<<dim3(MROWS / 128, NQKV / 128), 256, 0, stream>>>(
        qs_bf, kvs_bf, Wt, Qb, Kb, Vtb, nullptr, nullptr);
    attn_kernel<<<dim3(NB * HEADS, NQ / 64), 256, 0, stream>>>(Qb, Kb, Vtb, Xb);
    gemm_bk64<1, 64><<<dim3(MROWS / 128, DIM / 64), 256, 0, stream>>>(
        Xb, nullptr, Wprojt, nullptr, nullptr, nullptr, out, bproj);
}